// Round 5
// baseline (589.870 us; speedup 1.0000x reference)
//
#include <hip/hip_runtime.h>

// LightGCN propagation, MI355X. Round 9.
// R6-R8 evidence: spmm dur/FETCH ratio constant ~3.5-3.8 TB/s across 3
// structures -> BW-bound on L2-miss path; only lever is FETCH bytes.
// R8 FETCH/layer = 496MB: col 25.6 + emb0-f32 38.4 + gather-miss ~430.
// Build residual ~190us for p1+p2 >> ~25us BW cost -> p1 LDS-atomic bound
// (512 thr on 586 shared counters).
// R9: (1) alpha term read from fp16 h0 (-19.2MB/layer, err ~2e-6);
//     (2) per-side temporal spmm split: user pass (6.4MB footprint), item
//         pass (12.8MB) instead of mixed 19.2MB in each XCD's 4MB L2;
//     (3) phase1 per-wave private histograms (8x586) -> same-address LDS
//         atomic collisions intra-wave only.
// Tiers: A2 (h0+h1 in ws) / A (h1 in ws, h0 in u2, layer-2 alpha f32) /
//        B (no h1: layer1 fp16 gather, layer2 f32) / C atomic push.
//
// Inputs: [0] user_emb0 [100000,64] f32, [1] item_emb0 [50000,64] f32,
// [2] a_ui_vals [E] f32 (unused; ==1/deg_u), [3] a_iu_vals [E] f32 (unused),
// [4] edge_u [E] i32, [5] edge_i [E] i32.
// Output: user_layers [3,100000,64] then item_layers [3,50000,64], f32 flat.

constexpr int N_USERS = 100000;
constexpr int N_ITEMS = 50000;
constexpr int N_ROWS  = N_USERS + N_ITEMS;   // combined CSR rows
constexpr int D = 64;
constexpr int E_EDGES = 3200000;
constexpr float ALPHA = 0.1f;

constexpr long long NUF = (long long)N_USERS * D;  // 6,400,000
constexpr long long NIF = (long long)N_ITEMS * D;  // 3,200,000

// super-buckets: 256 combined rows each
constexpr int SB_SHIFT = 8;
constexpr int SB_ROWS  = 1 << SB_SHIFT;                       // 256
constexpr int NSB      = (N_ROWS + SB_ROWS - 1) >> SB_SHIFT;  // 586
constexpr int CAP      = 20480;  // static slots per bucket; worst count ~16.9K

constexpr int P1_EDGES   = 8192;   // edges per block-chunk in phase1
constexpr int P1_THREADS = 512;
constexpr int P1_WAVES   = P1_THREADS / 64;        // 8
constexpr int P1_EPT     = P1_EDGES / P1_THREADS;  // 16 edges/thread
constexpr int P2_THREADS = 512;

// ---------------- output layer 0 ----------------
__global__ void init_layer0(const float* __restrict__ uemb,
                            const float* __restrict__ iemb,
                            float* __restrict__ out) {
    long long idx = (long long)blockIdx.x * blockDim.x + threadIdx.x;
    if (idx < NUF) out[idx] = uemb[idx];
    if (idx < NIF) out[3 * NUF + idx] = iemb[idx];
}

// Fallback-only: seed layers 1,2 with ALPHA*emb0.
__global__ void seed_alpha(const float* __restrict__ uemb,
                           const float* __restrict__ iemb,
                           float* __restrict__ out) {
    long long idx = (long long)blockIdx.x * blockDim.x + threadIdx.x;
    if (idx < NUF) {
        float av = ALPHA * uemb[idx];
        out[NUF + idx] = av;
        out[2 * NUF + idx] = av;
    }
    if (idx < NIF) {
        float av = ALPHA * iemb[idx];
        out[3 * NUF + NIF + idx] = av;
        out[3 * NUF + 2 * NIF + idx] = av;
    }
}

// ---------------- bucket cursors at static offsets ----------------
__global__ void init_sbcur(int* __restrict__ sbcur) {
    int t = blockIdx.x * blockDim.x + threadIdx.x;
    if (t < NSB) sbcur[t] = t * CAP;
}

// After phase1: counts = sbcur[t] - t*CAP; exclusive scan -> sbstart.
__global__ void count_scan(const int* __restrict__ sbcur, int* __restrict__ sbstart) {
    __shared__ int sh[1024];
    int t = threadIdx.x;
    int v = (t < NSB) ? (sbcur[t] - t * CAP) : 0;
    sh[t] = v;
    __syncthreads();
    for (int off = 1; off < 1024; off <<= 1) {
        int x = (t >= off) ? sh[t - off] : 0;
        __syncthreads();
        sh[t] += x;
        __syncthreads();
    }
    if (t < NSB) {
        sbstart[t] = sh[t] - v;
        if (t == NSB - 1) sbstart[NSB] = sh[t];
    }
}

// ---------------- phase 1: bucketed bin-sort of edge endpoints ----------------
// scratch entry: (local_row << 17) | src   (local_row < 256, src < 2^17)
// scratch is bucketed at static offsets sb*CAP. Per-wave private histograms:
// same-address LDS atomic collisions are intra-wave only.
__global__ void phase1_binsort(const int* __restrict__ eu, const int* __restrict__ ei,
                               int* __restrict__ sbcur, unsigned* __restrict__ scratch) {
    __shared__ int whist[P1_WAVES][NSB];   // 18.75 KB
    __shared__ int gbase[NSB];
    int t = threadIdx.x;
    int w = t >> 6;                        // wave id
    int nchunks = (E_EDGES + P1_EDGES - 1) / P1_EDGES;
    for (int c = blockIdx.x; c < nchunks; c += gridDim.x) {
        int lo = c * P1_EDGES;
        for (int r = t; r < P1_WAVES * NSB; r += P1_THREADS)
            ((int*)whist)[r] = 0;
        __syncthreads();
        unsigned sbr[2 * P1_EPT];
        unsigned val[2 * P1_EPT];
#pragma unroll
        for (int k = 0; k < P1_EPT; k++) {
            int e = lo + k * P1_THREADS + t;
            if (e < E_EDGES) {
                int u = __builtin_nontemporal_load(eu + e);
                int i = __builtin_nontemporal_load(ei + e);
                int r0 = u;             // user combined row
                int r1 = N_USERS + i;   // item combined row
                int sb0 = r0 >> SB_SHIFT;
                int sb1 = r1 >> SB_SHIFT;
                int rk0 = atomicAdd(&whist[w][sb0], 1);
                int rk1 = atomicAdd(&whist[w][sb1], 1);
                sbr[2 * k]     = ((unsigned)sb0 << 16) | (unsigned)rk0;
                val[2 * k]     = ((unsigned)(r0 & (SB_ROWS - 1)) << 17) | (unsigned)i;
                sbr[2 * k + 1] = ((unsigned)sb1 << 16) | (unsigned)rk1;
                val[2 * k + 1] = ((unsigned)(r1 & (SB_ROWS - 1)) << 17) | (unsigned)u;
            } else {
                sbr[2 * k]     = 0xFFFFFFFFu;
                sbr[2 * k + 1] = 0xFFFFFFFFu;
            }
        }
        __syncthreads();
        // combine per-wave counts -> per-wave exclusive prefixes + global base
        for (int r = t; r < NSB; r += P1_THREADS) {
            int tot = 0;
#pragma unroll
            for (int ww = 0; ww < P1_WAVES; ww++) {
                int x = whist[ww][r];
                whist[ww][r] = tot;
                tot += x;
            }
            gbase[r] = tot ? atomicAdd(&sbcur[r], tot) : 0;
        }
        __syncthreads();
#pragma unroll
        for (int k = 0; k < 2 * P1_EPT; k++) {
            if (sbr[k] != 0xFFFFFFFFu) {
                int sb = (int)(sbr[k] >> 16);
                int rk = (int)(sbr[k] & 0xFFFFu);
                int p  = gbase[sb] + whist[w][sb] + rk;
                if (p < (sb + 1) * CAP)  // OOB guard (never triggers: 32-sigma)
                    scratch[p] = val[k];
            }
        }
        __syncthreads();  // protect whist/gbase before next chunk
    }
}

// ---------------- phase 2: per-bucket LDS reorder -> row[] + streaming col[] --
__global__ void phase2_fused(const unsigned* __restrict__ scratch,
                             const int* __restrict__ sbcur,
                             const int* __restrict__ sbstart,
                             int* __restrict__ row, int* __restrict__ col) {
    __shared__ unsigned buf[CAP];
    __shared__ int hist[SB_ROWS];
    __shared__ int pscan[SB_ROWS];
    int sb = blockIdx.x;
    int t = threadIdx.x;
    int lo = sb * CAP;
    int n  = sbcur[sb] - lo;
    if (n > CAP) n = CAP;            // guard (never triggers)
    int out_lo = sbstart[sb];
    if (t < SB_ROWS) hist[t] = 0;
    __syncthreads();
    // pass 1: row histogram (bucket ~64-80KB -> L2-hot for pass 2)
    for (int idx = t; idx < n; idx += P2_THREADS)
        atomicAdd(&hist[scratch[lo + idx] >> 17], 1);
    __syncthreads();
    if (t < SB_ROWS) pscan[t] = hist[t];
    __syncthreads();
    for (int off = 1; off < SB_ROWS; off <<= 1) {
        int x = 0;
        if (t < SB_ROWS && t >= off) x = pscan[t - off];
        __syncthreads();
        if (t < SB_ROWS) pscan[t] += x;
        __syncthreads();
    }
    int excl = 0;
    if (t < SB_ROWS) {
        excl = pscan[t] - hist[t];
        int gr = (sb << SB_SHIFT) + t;
        if (gr <= N_ROWS) row[gr] = out_lo + excl;  // also covers row[N_ROWS]
    }
    __syncthreads();
    if (t < SB_ROWS) hist[t] = excl;  // becomes the write cursor
    __syncthreads();
    // pass 2: rank via LDS cursor, scatter into LDS
    for (int idx = t; idx < n; idx += P2_THREADS) {
        unsigned e = scratch[lo + idx];
        int p = atomicAdd(&hist[e >> 17], 1);
        buf[p] = e & 0x1FFFFu;
    }
    __syncthreads();
    // pass 3: stream out (coalesced sequential stores)
    for (int k = t; k < n; k += P2_THREADS)
        col[out_lo + k] = (int)buf[k];
}

// ---------------- emb0 -> fp16 tables ----------------
__global__ void emb_to_half(const float* __restrict__ uemb,
                            const float* __restrict__ iemb,
                            _Float16* __restrict__ hu, _Float16* __restrict__ hi) {
    long long idx = ((long long)blockIdx.x * blockDim.x + threadIdx.x) * 4;
    if (idx < NUF) {
        float4 v = *(const float4*)(uemb + idx);
        _Float16 h4[4] = {(_Float16)v.x, (_Float16)v.y, (_Float16)v.z, (_Float16)v.w};
        *(uint2*)(hu + idx) = *(const uint2*)h4;
    } else if (idx < NUF + NIF) {
        long long k = idx - NUF;
        float4 v = *(const float4*)(iemb + k);
        _Float16 h4[4] = {(_Float16)v.x, (_Float16)v.y, (_Float16)v.z, (_Float16)v.w};
        *(uint2*)(hi + k) = *(const uint2*)h4;
    }
}

// ---------------- pull SPMM, fp16 gather ----------------
__device__ __forceinline__ void pull_row_h2(const int* __restrict__ row,
                                            const int* __restrict__ col,
                                            const _Float16* __restrict__ hsrc,
                                            const _Float16* __restrict__ e0h,
                                            const float* __restrict__ e0f,
                                            float* __restrict__ dst,
                                            _Float16* __restrict__ hdst,
                                            int comb_row, int local_row, int lane) {
    int start = __builtin_amdgcn_readfirstlane(row[comb_row]);
    int end   = __builtin_amdgcn_readfirstlane(row[comb_row + 1]);
    int len = end - start;
    float scale = (len > 0) ? 1.0f / (float)len : 0.0f;

    float acc0 = 0.f, acc1 = 0.f, acc2 = 0.f, acc3 = 0.f;
    int j = start;
    for (; j + 8 <= end; j += 8) {
        int c0 = __builtin_nontemporal_load(col + j + 0);
        int c1 = __builtin_nontemporal_load(col + j + 1);
        int c2 = __builtin_nontemporal_load(col + j + 2);
        int c3 = __builtin_nontemporal_load(col + j + 3);
        int c4 = __builtin_nontemporal_load(col + j + 4);
        int c5 = __builtin_nontemporal_load(col + j + 5);
        int c6 = __builtin_nontemporal_load(col + j + 6);
        int c7 = __builtin_nontemporal_load(col + j + 7);
        acc0 += (float)hsrc[((long long)c0 << 6) + lane];
        acc1 += (float)hsrc[((long long)c1 << 6) + lane];
        acc2 += (float)hsrc[((long long)c2 << 6) + lane];
        acc3 += (float)hsrc[((long long)c3 << 6) + lane];
        acc0 += (float)hsrc[((long long)c4 << 6) + lane];
        acc1 += (float)hsrc[((long long)c5 << 6) + lane];
        acc2 += (float)hsrc[((long long)c6 << 6) + lane];
        acc3 += (float)hsrc[((long long)c7 << 6) + lane];
    }
    for (; j < end; j++) {
        int c = __builtin_nontemporal_load(col + j);
        acc0 += (float)hsrc[((long long)c << 6) + lane];
    }
    long long li = ((long long)local_row << 6) + lane;
    float e0 = e0h ? (float)e0h[li] : e0f[li];
    float res = scale * ((acc0 + acc1) + (acc2 + acc3)) + ALPHA * e0;
    __builtin_nontemporal_store(res, dst + li);
    if (hdst) hdst[li] = (_Float16)res;
}

// user rows only: gather from fp16 item table (6.4MB footprint).
__global__ void spmm_user_h(const int* __restrict__ row, const int* __restrict__ col,
                            const _Float16* __restrict__ hsrc_item,
                            const _Float16* __restrict__ e0h,
                            const float* __restrict__ e0f,
                            float* __restrict__ out_user,
                            _Float16* __restrict__ hout_user) {
    long long gtid = (long long)blockIdx.x * blockDim.x + threadIdx.x;
    int wave = (int)(gtid >> 6);
    int lane = (int)(gtid & 63);
    if (wave >= N_USERS) return;
    pull_row_h2(row, col, hsrc_item, e0h, e0f, out_user, hout_user,
                wave, wave, lane);
}

// item rows only: gather from fp16 user table (12.8MB footprint).
__global__ void spmm_item_h(const int* __restrict__ row, const int* __restrict__ col,
                            const _Float16* __restrict__ hsrc_user,
                            const _Float16* __restrict__ e0h,
                            const float* __restrict__ e0f,
                            float* __restrict__ out_item,
                            _Float16* __restrict__ hout_item) {
    long long gtid = (long long)blockIdx.x * blockDim.x + threadIdx.x;
    int wave = (int)(gtid >> 6);
    int lane = (int)(gtid & 63);
    if (wave >= N_ITEMS) return;
    pull_row_h2(row, col, hsrc_user, e0h, e0f, out_item, hout_item,
                N_USERS + wave, wave, lane);
}

// ---------------- pull SPMM, f32 gather (tier B layer 2) ----------------
__global__ void spmm_pull(const int* __restrict__ row, const int* __restrict__ col,
                          const float* __restrict__ src_user,
                          const float* __restrict__ src_item,
                          const float* __restrict__ uemb, const float* __restrict__ iemb,
                          float* __restrict__ out_user, float* __restrict__ out_item) {
    long long gtid = (long long)blockIdx.x * blockDim.x + threadIdx.x;
    int wave = (int)(gtid >> 6);
    int lane = (int)(gtid & 63);
    if (wave >= N_ROWS) return;
    const float* src; const float* emb0; float* dst; int r;
    if (wave < N_USERS) {
        r = wave; src = src_item; emb0 = uemb; dst = out_user;
    } else {
        r = wave - N_USERS; src = src_user; emb0 = iemb; dst = out_item;
    }
    int start = __builtin_amdgcn_readfirstlane(row[wave]);
    int end   = __builtin_amdgcn_readfirstlane(row[wave + 1]);
    int len = end - start;
    float scale = (len > 0) ? 1.0f / (float)len : 0.0f;

    float acc0 = 0.f, acc1 = 0.f, acc2 = 0.f, acc3 = 0.f;
    int j = start;
    for (; j + 8 <= end; j += 8) {
        int c0 = col[j + 0], c1 = col[j + 1], c2 = col[j + 2], c3 = col[j + 3];
        int c4 = col[j + 4], c5 = col[j + 5], c6 = col[j + 6], c7 = col[j + 7];
        acc0 += src[((long long)c0 << 6) + lane];
        acc1 += src[((long long)c1 << 6) + lane];
        acc2 += src[((long long)c2 << 6) + lane];
        acc3 += src[((long long)c3 << 6) + lane];
        acc0 += src[((long long)c4 << 6) + lane];
        acc1 += src[((long long)c5 << 6) + lane];
        acc2 += src[((long long)c6 << 6) + lane];
        acc3 += src[((long long)c7 << 6) + lane];
    }
    for (; j < end; j++) {
        int c = col[j];
        acc0 += src[((long long)c << 6) + lane];
    }
    float res = scale * ((acc0 + acc1) + (acc2 + acc3))
              + ALPHA * emb0[((long long)r << 6) + lane];
    dst[((long long)r << 6) + lane] = res;
}

// ---------------- fallback (atomic push) ----------------
__global__ void spmm_layer_atomic(const float* __restrict__ a_ui,
                                  const float* __restrict__ a_iu,
                                  const int* __restrict__ edge_u,
                                  const int* __restrict__ edge_i,
                                  const float* __restrict__ src_user,
                                  const float* __restrict__ src_item,
                                  float* __restrict__ dst_user,
                                  float* __restrict__ dst_item) {
    long long gtid = (long long)blockIdx.x * blockDim.x + threadIdx.x;
    long long wave = gtid >> 6;
    int lane = (int)(gtid & 63);
    if (wave < (long long)E_EDGES) {
        int e = (int)wave;
        int u = edge_u[e];
        int i = edge_i[e];
        float x = a_ui[e] * src_item[(long long)i * D + lane];
        __hip_atomic_fetch_add(dst_user + (long long)u * D + lane, x,
                               __ATOMIC_RELAXED, __HIP_MEMORY_SCOPE_AGENT);
    } else if (wave < 2LL * E_EDGES) {
        int e = (int)(wave - E_EDGES);
        int u = edge_u[e];
        int i = edge_i[e];
        float x = a_iu[e] * src_user[(long long)u * D + lane];
        __hip_atomic_fetch_add(dst_item + (long long)i * D + lane, x,
                               __ATOMIC_RELAXED, __HIP_MEMORY_SCOPE_AGENT);
    }
}

extern "C" void kernel_launch(void* const* d_in, const int* in_sizes, int n_in,
                              void* d_out, int out_size, void* d_ws, size_t ws_size,
                              hipStream_t stream) {
    const float* uemb   = (const float*)d_in[0];
    const float* iemb   = (const float*)d_in[1];
    const float* a_ui   = (const float*)d_in[2];
    const float* a_iu   = (const float*)d_in[3];
    const int*   edge_u = (const int*)d_in[4];
    const int*   edge_i = (const int*)d_in[5];
    float* out = (float*)d_out;

    float* u1 = out + NUF;
    float* u2 = out + 2 * NUF;
    float* i1 = out + 3 * NUF + NIF;
    float* i2 = out + 3 * NUF + 2 * NIF;

    // Padded bucketed scratch at static offsets aliases u1+u2 (dead until the
    // spmm layers run): NSB*CAP = 12,001,280 u32 <= 12.8M floats (u1+u2).
    unsigned* scratch = (unsigned*)u1;

    size_t base_ints = (size_t)(N_ROWS + 1) + NSB + (NSB + 1) + 2 * (size_t)E_EDGES;
    size_t need_b  = base_ints * 4 + 64;
    size_t need_a  = need_b + (size_t)(NUF + NIF) * 2;   // + h1
    size_t need_a2 = need_a + (size_t)(NUF + NIF) * 2;   // + h0 in ws
    bool tier_b  = ws_size >= need_b;
    bool tier_a  = ws_size >= need_a;
    bool tier_a2 = ws_size >= need_a2;

    {
        const int threads = 256;
        const int blocks = (int)((NUF + threads - 1) / threads);
        init_layer0<<<blocks, threads, 0, stream>>>(uemb, iemb, out);
    }

    if (tier_b) {
        int* w = (int*)d_ws;
        int* row     = w;  w += N_ROWS + 1;
        int* sbcur   = w;  w += NSB;
        int* sbstart = w;  w += NSB + 1;
        int* col     = w;  w += 2 * E_EDGES;
        _Float16* h1u = (_Float16*)w;            // tier A+
        _Float16* h1i = h1u + NUF;
        _Float16* h0u = tier_a2 ? (h1i + NIF)    // tier A2: h0 in ws
                                : (_Float16*)u2; // tier A/B: h0 in dead u2
        _Float16* h0i = h0u + NUF;

        init_sbcur<<<3, 256, 0, stream>>>(sbcur);
        const int p1_blocks = (E_EDGES + P1_EDGES - 1) / P1_EDGES;  // 391
        phase1_binsort<<<p1_blocks, P1_THREADS, 0, stream>>>(edge_u, edge_i,
                                                             sbcur, scratch);
        count_scan<<<1, 1024, 0, stream>>>(sbcur, sbstart);
        phase2_fused<<<NSB, P2_THREADS, 0, stream>>>(scratch, sbcur, sbstart,
                                                     row, col);
        // scratch consumed; convert emb0 -> h0.
        {
            const long long quads = (NUF + NIF) / 4;
            const int blocks = (int)((quads + 255) / 256);
            emb_to_half<<<blocks, 256, 0, stream>>>(uemb, iemb, h0u, h0i);
        }

        const int ublocks = (int)(((long long)N_USERS * 64 + 255) / 256);  // 25000
        const int iblocks = (int)(((long long)N_ITEMS * 64 + 255) / 256);  // 12500
        if (tier_a) {
            // layer 1: fp16 gather + fp16 alpha; emit h1. (h0 in u2 is safe:
            // layer-1 dsts are u1/i1.)
            spmm_user_h<<<ublocks, 256, 0, stream>>>(row, col, h0i, h0u, nullptr,
                                                     u1, h1u);
            spmm_item_h<<<iblocks, 256, 0, stream>>>(row, col, h0u, h0i, nullptr,
                                                     i1, h1i);
            // layer 2: fp16 gather from h1. Alpha: fp16 only if h0 lives in ws
            // (tier A2); else f32 (u2 is being overwritten).
            const _Float16* a2u = tier_a2 ? h0u : nullptr;
            const _Float16* a2i = tier_a2 ? h0i : nullptr;
            spmm_user_h<<<ublocks, 256, 0, stream>>>(row, col, h1i, a2u, uemb,
                                                     u2, nullptr);
            spmm_item_h<<<iblocks, 256, 0, stream>>>(row, col, h1u, a2i, iemb,
                                                     i2, nullptr);
        } else {
            // tier B: layer 1 fp16 gather (no h1), layer 2 f32 gather.
            spmm_user_h<<<ublocks, 256, 0, stream>>>(row, col, h0i, h0u, nullptr,
                                                     u1, nullptr);
            spmm_item_h<<<iblocks, 256, 0, stream>>>(row, col, h0u, h0i, nullptr,
                                                     i1, nullptr);
            const int threads = 256;
            const long long total_threads = (long long)N_ROWS * 64;
            const int blocks = (int)((total_threads + threads - 1) / threads);
            spmm_pull<<<blocks, threads, 0, stream>>>(row, col, u1, i1,
                                                      uemb, iemb, u2, i2);
        }
    } else {
        {
            const int threads = 256;
            const int blocks = (int)((NUF + threads - 1) / threads);
            seed_alpha<<<blocks, threads, 0, stream>>>(uemb, iemb, out);
        }
        const int threads = 256;
        const long long total_threads = 2LL * E_EDGES * 64;
        const int blocks = (int)((total_threads + threads - 1) / threads);
        spmm_layer_atomic<<<blocks, threads, 0, stream>>>(a_ui, a_iu, edge_u, edge_i,
                                                          uemb, iemb, u1, i1);
        spmm_layer_atomic<<<blocks, threads, 0, stream>>>(a_ui, a_iu, edge_u, edge_i,
                                                          u1, i1, u2, i2);
    }
}

// Round 6
// 564.771 us; speedup vs baseline: 1.0444x; 1.0444x over previous
//
#include <hip/hip_runtime.h>

// LightGCN propagation, MI355X. Round 10.
// R9 post-mortem: per-wave hists REGRESSED build (+50us LDS overhead) ->
// phase1 cost is NOT atomic collisions. Revised theory: it's the uncoalesced
// scatter (64 lanes -> 64 different buckets = 64 x 4B transactions per wave
// store; 6.4M scattered stores). R10 phase1: chunk-level LDS counting-sort -
// rank 16384 entries into 64KB LDS buf (atomic return = intra-chunk rank,
// 586-bin chunk-local scan = bucket offsets), then write bucket runs with
// consecutive lanes = coalesced ~112B runs. LDS 73KB -> 2 blocks/CU.
// Keep R9 spmm split (worked: item FETCH 299MB matches hit=L2/footprint
// model) + fp16 tiers. Tier A2: fuse emb->h0 into init_layer0 (-38MB pass).
//
// Inputs: [0] user_emb0 [100000,64] f32, [1] item_emb0 [50000,64] f32,
// [2] a_ui_vals [E] f32 (unused; ==1/deg_u), [3] a_iu_vals [E] f32 (unused),
// [4] edge_u [E] i32, [5] edge_i [E] i32.
// Output: user_layers [3,100000,64] then item_layers [3,50000,64], f32 flat.

constexpr int N_USERS = 100000;
constexpr int N_ITEMS = 50000;
constexpr int N_ROWS  = N_USERS + N_ITEMS;   // combined CSR rows
constexpr int D = 64;
constexpr int E_EDGES = 3200000;
constexpr float ALPHA = 0.1f;

constexpr long long NUF = (long long)N_USERS * D;  // 6,400,000
constexpr long long NIF = (long long)N_ITEMS * D;  // 3,200,000

// super-buckets: 256 combined rows each
constexpr int SB_SHIFT = 8;
constexpr int SB_ROWS  = 1 << SB_SHIFT;                       // 256
constexpr int NSB      = (N_ROWS + SB_ROWS - 1) >> SB_SHIFT;  // 586
constexpr int CAP      = 20480;  // static slots per bucket; worst count ~16.9K

constexpr int P1_EDGES   = 8192;   // edges per block-chunk in phase1
constexpr int P1_THREADS = 512;
constexpr int P1_EPT     = P1_EDGES / P1_THREADS;  // 16 edges/thread
constexpr int P2_THREADS = 512;

// ---------------- output layer 0 ----------------
__global__ void init_layer0(const float* __restrict__ uemb,
                            const float* __restrict__ iemb,
                            float* __restrict__ out) {
    long long idx = (long long)blockIdx.x * blockDim.x + threadIdx.x;
    if (idx < NUF) out[idx] = uemb[idx];
    if (idx < NIF) out[3 * NUF + idx] = iemb[idx];
}

// Tier A2: layer0 copy + fp16 conversion in one pass (h0 in ws, no alias).
__global__ void init_layer0_fused(const float* __restrict__ uemb,
                                  const float* __restrict__ iemb,
                                  float* __restrict__ out,
                                  _Float16* __restrict__ h0u,
                                  _Float16* __restrict__ h0i) {
    long long idx = ((long long)blockIdx.x * blockDim.x + threadIdx.x) * 4;
    if (idx < NUF) {
        float4 v = *(const float4*)(uemb + idx);
        *(float4*)(out + idx) = v;
        _Float16 h4[4] = {(_Float16)v.x, (_Float16)v.y, (_Float16)v.z, (_Float16)v.w};
        *(uint2*)(h0u + idx) = *(const uint2*)h4;
    }
    if (idx < NIF) {
        float4 v = *(const float4*)(iemb + idx);
        *(float4*)(out + 3 * NUF + idx) = v;
        _Float16 h4[4] = {(_Float16)v.x, (_Float16)v.y, (_Float16)v.z, (_Float16)v.w};
        *(uint2*)(h0i + idx) = *(const uint2*)h4;
    }
}

// Fallback-only: seed layers 1,2 with ALPHA*emb0.
__global__ void seed_alpha(const float* __restrict__ uemb,
                           const float* __restrict__ iemb,
                           float* __restrict__ out) {
    long long idx = (long long)blockIdx.x * blockDim.x + threadIdx.x;
    if (idx < NUF) {
        float av = ALPHA * uemb[idx];
        out[NUF + idx] = av;
        out[2 * NUF + idx] = av;
    }
    if (idx < NIF) {
        float av = ALPHA * iemb[idx];
        out[3 * NUF + NIF + idx] = av;
        out[3 * NUF + 2 * NIF + idx] = av;
    }
}

// ---------------- bucket cursors at static offsets ----------------
__global__ void init_sbcur(int* __restrict__ sbcur) {
    int t = blockIdx.x * blockDim.x + threadIdx.x;
    if (t < NSB) sbcur[t] = t * CAP;
}

// After phase1: counts = sbcur[t] - t*CAP; exclusive scan -> sbstart.
__global__ void count_scan(const int* __restrict__ sbcur, int* __restrict__ sbstart) {
    __shared__ int sh[1024];
    int t = threadIdx.x;
    int v = (t < NSB) ? (sbcur[t] - t * CAP) : 0;
    sh[t] = v;
    __syncthreads();
    for (int off = 1; off < 1024; off <<= 1) {
        int x = (t >= off) ? sh[t - off] : 0;
        __syncthreads();
        sh[t] += x;
        __syncthreads();
    }
    if (t < NSB) {
        sbstart[t] = sh[t] - v;
        if (t == NSB - 1) sbstart[NSB] = sh[t];
    }
}

// ---------------- phase 1: bucketed bin-sort, coalesced run writes ----------
// scratch entry: (local_row << 17) | src   (local_row < 256, src < 2^17)
// scratch bucketed at static offsets sb*CAP. Per chunk: count (atomic return
// = intra-chunk rank) -> chunk-local scan -> rank into LDS buf ordered by
// bucket -> stream runs out with consecutive lanes (coalesced).
__global__ void phase1_binsort(const int* __restrict__ eu, const int* __restrict__ ei,
                               int* __restrict__ sbcur, unsigned* __restrict__ scratch) {
    __shared__ unsigned buf[2 * P1_EDGES];  // 64 KB
    __shared__ int hist[NSB];
    __shared__ int excl[NSB];
    __shared__ int gbase[NSB];
    __shared__ int psc[P1_THREADS];
    int t = threadIdx.x;
    int wv = t >> 6;
    int lane = t & 63;
    int nchunks = (E_EDGES + P1_EDGES - 1) / P1_EDGES;
    for (int c = blockIdx.x; c < nchunks; c += gridDim.x) {
        int lo = c * P1_EDGES;
        for (int r = t; r < NSB; r += P1_THREADS) hist[r] = 0;
        __syncthreads();
        unsigned sbr[2 * P1_EPT];
        unsigned val[2 * P1_EPT];
#pragma unroll
        for (int k = 0; k < P1_EPT; k++) {
            int e = lo + k * P1_THREADS + t;
            if (e < E_EDGES) {
                int u = __builtin_nontemporal_load(eu + e);
                int i = __builtin_nontemporal_load(ei + e);
                int r0 = u;             // user combined row
                int r1 = N_USERS + i;   // item combined row
                int sb0 = r0 >> SB_SHIFT;
                int sb1 = r1 >> SB_SHIFT;
                int rk0 = atomicAdd(&hist[sb0], 1);
                int rk1 = atomicAdd(&hist[sb1], 1);
                sbr[2 * k]     = ((unsigned)sb0 << 16) | (unsigned)rk0;
                val[2 * k]     = ((unsigned)(r0 & (SB_ROWS - 1)) << 17) | (unsigned)i;
                sbr[2 * k + 1] = ((unsigned)sb1 << 16) | (unsigned)rk1;
                val[2 * k + 1] = ((unsigned)(r1 & (SB_ROWS - 1)) << 17) | (unsigned)u;
            } else {
                sbr[2 * k]     = 0xFFFFFFFFu;
                sbr[2 * k + 1] = 0xFFFFFFFFu;
            }
        }
        __syncthreads();
        // chunk-local exclusive scan over 586 bins (2 bins/thread) + global base
        int a = (2 * t < NSB) ? hist[2 * t] : 0;
        int b = (2 * t + 1 < NSB) ? hist[2 * t + 1] : 0;
        psc[t] = a + b;
        __syncthreads();
        for (int off = 1; off < P1_THREADS; off <<= 1) {
            int x = (t >= off) ? psc[t - off] : 0;
            __syncthreads();
            psc[t] += x;
            __syncthreads();
        }
        int e0 = psc[t] - (a + b);
        if (2 * t < NSB)     excl[2 * t] = e0;
        if (2 * t + 1 < NSB) excl[2 * t + 1] = e0 + a;
        for (int r = t; r < NSB; r += P1_THREADS) {
            int cnt = hist[r];
            gbase[r] = cnt ? atomicAdd(&sbcur[r], cnt) : 0;
        }
        __syncthreads();
        // rank-scatter into LDS buf (ordered by bucket)
#pragma unroll
        for (int k = 0; k < 2 * P1_EPT; k++) {
            if (sbr[k] != 0xFFFFFFFFu) {
                int sb = (int)(sbr[k] >> 16);
                int rk = (int)(sbr[k] & 0xFFFFu);
                buf[excl[sb] + rk] = val[k];
            }
        }
        __syncthreads();
        // stream runs out: consecutive lanes -> consecutive scratch addrs
        for (int r = wv; r < NSB; r += P1_THREADS / 64) {
            int cnt  = hist[r];
            int base = gbase[r];
            int off  = excl[r];
            int cap_hi = (r + 1) * CAP;
            for (int k = lane; k < cnt; k += 64) {
                int p = base + k;
                if (p < cap_hi)  // OOB guard (never triggers: 32-sigma)
                    scratch[p] = buf[off + k];
            }
        }
        __syncthreads();  // protect hist/excl/gbase/buf before next chunk
    }
}

// ---------------- phase 2: per-bucket LDS reorder -> row[] + streaming col[] --
__global__ void phase2_fused(const unsigned* __restrict__ scratch,
                             const int* __restrict__ sbcur,
                             const int* __restrict__ sbstart,
                             int* __restrict__ row, int* __restrict__ col) {
    __shared__ unsigned buf[CAP];
    __shared__ int hist[SB_ROWS];
    __shared__ int pscan[SB_ROWS];
    int sb = blockIdx.x;
    int t = threadIdx.x;
    int lo = sb * CAP;
    int n  = sbcur[sb] - lo;
    if (n > CAP) n = CAP;            // guard (never triggers)
    int out_lo = sbstart[sb];
    if (t < SB_ROWS) hist[t] = 0;
    __syncthreads();
    // pass 1: row histogram (bucket ~64-80KB -> L2-hot for pass 2)
    for (int idx = t; idx < n; idx += P2_THREADS)
        atomicAdd(&hist[scratch[lo + idx] >> 17], 1);
    __syncthreads();
    if (t < SB_ROWS) pscan[t] = hist[t];
    __syncthreads();
    for (int off = 1; off < SB_ROWS; off <<= 1) {
        int x = 0;
        if (t < SB_ROWS && t >= off) x = pscan[t - off];
        __syncthreads();
        if (t < SB_ROWS) pscan[t] += x;
        __syncthreads();
    }
    int excl = 0;
    if (t < SB_ROWS) {
        excl = pscan[t] - hist[t];
        int gr = (sb << SB_SHIFT) + t;
        if (gr <= N_ROWS) row[gr] = out_lo + excl;  // also covers row[N_ROWS]
    }
    __syncthreads();
    if (t < SB_ROWS) hist[t] = excl;  // becomes the write cursor
    __syncthreads();
    // pass 2: rank via LDS cursor, scatter into LDS
    for (int idx = t; idx < n; idx += P2_THREADS) {
        unsigned e = scratch[lo + idx];
        int p = atomicAdd(&hist[e >> 17], 1);
        buf[p] = e & 0x1FFFFu;
    }
    __syncthreads();
    // pass 3: stream out (coalesced sequential stores)
    for (int k = t; k < n; k += P2_THREADS)
        col[out_lo + k] = (int)buf[k];
}

// ---------------- emb0 -> fp16 tables (tier A/B: h0 in dead u2) ----------------
__global__ void emb_to_half(const float* __restrict__ uemb,
                            const float* __restrict__ iemb,
                            _Float16* __restrict__ hu, _Float16* __restrict__ hi) {
    long long idx = ((long long)blockIdx.x * blockDim.x + threadIdx.x) * 4;
    if (idx < NUF) {
        float4 v = *(const float4*)(uemb + idx);
        _Float16 h4[4] = {(_Float16)v.x, (_Float16)v.y, (_Float16)v.z, (_Float16)v.w};
        *(uint2*)(hu + idx) = *(const uint2*)h4;
    } else if (idx < NUF + NIF) {
        long long k = idx - NUF;
        float4 v = *(const float4*)(iemb + k);
        _Float16 h4[4] = {(_Float16)v.x, (_Float16)v.y, (_Float16)v.z, (_Float16)v.w};
        *(uint2*)(hi + k) = *(const uint2*)h4;
    }
}

// ---------------- pull SPMM, fp16 gather ----------------
__device__ __forceinline__ void pull_row_h2(const int* __restrict__ row,
                                            const int* __restrict__ col,
                                            const _Float16* __restrict__ hsrc,
                                            const _Float16* __restrict__ e0h,
                                            const float* __restrict__ e0f,
                                            float* __restrict__ dst,
                                            _Float16* __restrict__ hdst,
                                            int comb_row, int local_row, int lane) {
    int start = __builtin_amdgcn_readfirstlane(row[comb_row]);
    int end   = __builtin_amdgcn_readfirstlane(row[comb_row + 1]);
    int len = end - start;
    float scale = (len > 0) ? 1.0f / (float)len : 0.0f;

    float acc0 = 0.f, acc1 = 0.f, acc2 = 0.f, acc3 = 0.f;
    int j = start;
    for (; j + 8 <= end; j += 8) {
        int c0 = __builtin_nontemporal_load(col + j + 0);
        int c1 = __builtin_nontemporal_load(col + j + 1);
        int c2 = __builtin_nontemporal_load(col + j + 2);
        int c3 = __builtin_nontemporal_load(col + j + 3);
        int c4 = __builtin_nontemporal_load(col + j + 4);
        int c5 = __builtin_nontemporal_load(col + j + 5);
        int c6 = __builtin_nontemporal_load(col + j + 6);
        int c7 = __builtin_nontemporal_load(col + j + 7);
        acc0 += (float)hsrc[((long long)c0 << 6) + lane];
        acc1 += (float)hsrc[((long long)c1 << 6) + lane];
        acc2 += (float)hsrc[((long long)c2 << 6) + lane];
        acc3 += (float)hsrc[((long long)c3 << 6) + lane];
        acc0 += (float)hsrc[((long long)c4 << 6) + lane];
        acc1 += (float)hsrc[((long long)c5 << 6) + lane];
        acc2 += (float)hsrc[((long long)c6 << 6) + lane];
        acc3 += (float)hsrc[((long long)c7 << 6) + lane];
    }
    for (; j < end; j++) {
        int c = __builtin_nontemporal_load(col + j);
        acc0 += (float)hsrc[((long long)c << 6) + lane];
    }
    long long li = ((long long)local_row << 6) + lane;
    float e0 = e0h ? (float)e0h[li] : e0f[li];
    float res = scale * ((acc0 + acc1) + (acc2 + acc3)) + ALPHA * e0;
    __builtin_nontemporal_store(res, dst + li);
    if (hdst) hdst[li] = (_Float16)res;
}

// user rows only: gather from fp16 item table (6.4MB footprint).
__global__ void spmm_user_h(const int* __restrict__ row, const int* __restrict__ col,
                            const _Float16* __restrict__ hsrc_item,
                            const _Float16* __restrict__ e0h,
                            const float* __restrict__ e0f,
                            float* __restrict__ out_user,
                            _Float16* __restrict__ hout_user) {
    long long gtid = (long long)blockIdx.x * blockDim.x + threadIdx.x;
    int wave = (int)(gtid >> 6);
    int lane = (int)(gtid & 63);
    if (wave >= N_USERS) return;
    pull_row_h2(row, col, hsrc_item, e0h, e0f, out_user, hout_user,
                wave, wave, lane);
}

// item rows only: gather from fp16 user table (12.8MB footprint).
__global__ void spmm_item_h(const int* __restrict__ row, const int* __restrict__ col,
                            const _Float16* __restrict__ hsrc_user,
                            const _Float16* __restrict__ e0h,
                            const float* __restrict__ e0f,
                            float* __restrict__ out_item,
                            _Float16* __restrict__ hout_item) {
    long long gtid = (long long)blockIdx.x * blockDim.x + threadIdx.x;
    int wave = (int)(gtid >> 6);
    int lane = (int)(gtid & 63);
    if (wave >= N_ITEMS) return;
    pull_row_h2(row, col, hsrc_user, e0h, e0f, out_item, hout_item,
                N_USERS + wave, wave, lane);
}

// ---------------- pull SPMM, f32 gather (tier B layer 2) ----------------
__global__ void spmm_pull(const int* __restrict__ row, const int* __restrict__ col,
                          const float* __restrict__ src_user,
                          const float* __restrict__ src_item,
                          const float* __restrict__ uemb, const float* __restrict__ iemb,
                          float* __restrict__ out_user, float* __restrict__ out_item) {
    long long gtid = (long long)blockIdx.x * blockDim.x + threadIdx.x;
    int wave = (int)(gtid >> 6);
    int lane = (int)(gtid & 63);
    if (wave >= N_ROWS) return;
    const float* src; const float* emb0; float* dst; int r;
    if (wave < N_USERS) {
        r = wave; src = src_item; emb0 = uemb; dst = out_user;
    } else {
        r = wave - N_USERS; src = src_user; emb0 = iemb; dst = out_item;
    }
    int start = __builtin_amdgcn_readfirstlane(row[wave]);
    int end   = __builtin_amdgcn_readfirstlane(row[wave + 1]);
    int len = end - start;
    float scale = (len > 0) ? 1.0f / (float)len : 0.0f;

    float acc0 = 0.f, acc1 = 0.f, acc2 = 0.f, acc3 = 0.f;
    int j = start;
    for (; j + 8 <= end; j += 8) {
        int c0 = col[j + 0], c1 = col[j + 1], c2 = col[j + 2], c3 = col[j + 3];
        int c4 = col[j + 4], c5 = col[j + 5], c6 = col[j + 6], c7 = col[j + 7];
        acc0 += src[((long long)c0 << 6) + lane];
        acc1 += src[((long long)c1 << 6) + lane];
        acc2 += src[((long long)c2 << 6) + lane];
        acc3 += src[((long long)c3 << 6) + lane];
        acc0 += src[((long long)c4 << 6) + lane];
        acc1 += src[((long long)c5 << 6) + lane];
        acc2 += src[((long long)c6 << 6) + lane];
        acc3 += src[((long long)c7 << 6) + lane];
    }
    for (; j < end; j++) {
        int c = col[j];
        acc0 += src[((long long)c << 6) + lane];
    }
    float res = scale * ((acc0 + acc1) + (acc2 + acc3))
              + ALPHA * emb0[((long long)r << 6) + lane];
    dst[((long long)r << 6) + lane] = res;
}

// ---------------- fallback (atomic push) ----------------
__global__ void spmm_layer_atomic(const float* __restrict__ a_ui,
                                  const float* __restrict__ a_iu,
                                  const int* __restrict__ edge_u,
                                  const int* __restrict__ edge_i,
                                  const float* __restrict__ src_user,
                                  const float* __restrict__ src_item,
                                  float* __restrict__ dst_user,
                                  float* __restrict__ dst_item) {
    long long gtid = (long long)blockIdx.x * blockDim.x + threadIdx.x;
    long long wave = gtid >> 6;
    int lane = (int)(gtid & 63);
    if (wave < (long long)E_EDGES) {
        int e = (int)wave;
        int u = edge_u[e];
        int i = edge_i[e];
        float x = a_ui[e] * src_item[(long long)i * D + lane];
        __hip_atomic_fetch_add(dst_user + (long long)u * D + lane, x,
                               __ATOMIC_RELAXED, __HIP_MEMORY_SCOPE_AGENT);
    } else if (wave < 2LL * E_EDGES) {
        int e = (int)(wave - E_EDGES);
        int u = edge_u[e];
        int i = edge_i[e];
        float x = a_iu[e] * src_user[(long long)u * D + lane];
        __hip_atomic_fetch_add(dst_item + (long long)i * D + lane, x,
                               __ATOMIC_RELAXED, __HIP_MEMORY_SCOPE_AGENT);
    }
}

extern "C" void kernel_launch(void* const* d_in, const int* in_sizes, int n_in,
                              void* d_out, int out_size, void* d_ws, size_t ws_size,
                              hipStream_t stream) {
    const float* uemb   = (const float*)d_in[0];
    const float* iemb   = (const float*)d_in[1];
    const float* a_ui   = (const float*)d_in[2];
    const float* a_iu   = (const float*)d_in[3];
    const int*   edge_u = (const int*)d_in[4];
    const int*   edge_i = (const int*)d_in[5];
    float* out = (float*)d_out;

    float* u1 = out + NUF;
    float* u2 = out + 2 * NUF;
    float* i1 = out + 3 * NUF + NIF;
    float* i2 = out + 3 * NUF + 2 * NIF;

    // Padded bucketed scratch at static offsets aliases u1+u2 (dead until the
    // spmm layers run): NSB*CAP = 12,001,280 u32 <= 12.8M floats (u1+u2).
    unsigned* scratch = (unsigned*)u1;

    size_t base_ints = (size_t)(N_ROWS + 1) + NSB + (NSB + 1) + 2 * (size_t)E_EDGES;
    size_t need_b  = base_ints * 4 + 64;
    size_t need_a  = need_b + (size_t)(NUF + NIF) * 2;   // + h1
    size_t need_a2 = need_a + (size_t)(NUF + NIF) * 2;   // + h0 in ws
    bool tier_b  = ws_size >= need_b;
    bool tier_a  = ws_size >= need_a;
    bool tier_a2 = ws_size >= need_a2;

    if (tier_b) {
        int* w = (int*)d_ws;
        int* row     = w;  w += N_ROWS + 1;
        int* sbcur   = w;  w += NSB;
        int* sbstart = w;  w += NSB + 1;
        int* col     = w;  w += 2 * E_EDGES;
        _Float16* h1u = (_Float16*)w;            // tier A+
        _Float16* h1i = h1u + NUF;
        _Float16* h0u = tier_a2 ? (h1i + NIF)    // tier A2: h0 in ws
                                : (_Float16*)u2; // tier A/B: h0 in dead u2
        _Float16* h0i = h0u + NUF;

        if (tier_a2) {
            // fused layer-0 copy + fp16 conversion (h0 in ws: no scratch alias)
            const long long quads = NUF / 4;   // covers both (NIF/4 < NUF/4)
            const int blocks = (int)((quads + 255) / 256);
            init_layer0_fused<<<blocks, 256, 0, stream>>>(uemb, iemb, out,
                                                          h0u, h0i);
        } else {
            const int threads = 256;
            const int blocks = (int)((NUF + threads - 1) / threads);
            init_layer0<<<blocks, threads, 0, stream>>>(uemb, iemb, out);
        }

        init_sbcur<<<3, 256, 0, stream>>>(sbcur);
        const int p1_blocks = (E_EDGES + P1_EDGES - 1) / P1_EDGES;  // 391
        phase1_binsort<<<p1_blocks, P1_THREADS, 0, stream>>>(edge_u, edge_i,
                                                             sbcur, scratch);
        count_scan<<<1, 1024, 0, stream>>>(sbcur, sbstart);
        phase2_fused<<<NSB, P2_THREADS, 0, stream>>>(scratch, sbcur, sbstart,
                                                     row, col);
        if (!tier_a2) {
            // scratch consumed; convert emb0 -> h0 into dead u2.
            const long long quads = (NUF + NIF) / 4;
            const int blocks = (int)((quads + 255) / 256);
            emb_to_half<<<blocks, 256, 0, stream>>>(uemb, iemb, h0u, h0i);
        }

        const int ublocks = (int)(((long long)N_USERS * 64 + 255) / 256);  // 25000
        const int iblocks = (int)(((long long)N_ITEMS * 64 + 255) / 256);  // 12500
        if (tier_a) {
            // layer 1: fp16 gather + fp16 alpha; emit h1.
            spmm_user_h<<<ublocks, 256, 0, stream>>>(row, col, h0i, h0u, nullptr,
                                                     u1, h1u);
            spmm_item_h<<<iblocks, 256, 0, stream>>>(row, col, h0u, h0i, nullptr,
                                                     i1, h1i);
            // layer 2: fp16 gather from h1. Alpha fp16 only if h0 in ws (A2).
            const _Float16* a2u = tier_a2 ? h0u : nullptr;
            const _Float16* a2i = tier_a2 ? h0i : nullptr;
            spmm_user_h<<<ublocks, 256, 0, stream>>>(row, col, h1i, a2u, uemb,
                                                     u2, nullptr);
            spmm_item_h<<<iblocks, 256, 0, stream>>>(row, col, h1u, a2i, iemb,
                                                     i2, nullptr);
        } else {
            // tier B: layer 1 fp16 gather (no h1), layer 2 f32 gather.
            spmm_user_h<<<ublocks, 256, 0, stream>>>(row, col, h0i, h0u, nullptr,
                                                     u1, nullptr);
            spmm_item_h<<<iblocks, 256, 0, stream>>>(row, col, h0u, h0i, nullptr,
                                                     i1, nullptr);
            const int threads = 256;
            const long long total_threads = (long long)N_ROWS * 64;
            const int blocks = (int)((total_threads + threads - 1) / threads);
            spmm_pull<<<blocks, threads, 0, stream>>>(row, col, u1, i1,
                                                      uemb, iemb, u2, i2);
        }
    } else {
        {
            const int threads = 256;
            const int blocks = (int)((NUF + threads - 1) / threads);
            init_layer0<<<blocks, threads, 0, stream>>>(uemb, iemb, out);
            seed_alpha<<<blocks, threads, 0, stream>>>(uemb, iemb, out);
        }
        const int threads = 256;
        const long long total_threads = 2LL * E_EDGES * 64;
        const int blocks = (int)((total_threads + threads - 1) / threads);
        spmm_layer_atomic<<<blocks, threads, 0, stream>>>(a_ui, a_iu, edge_u, edge_i,
                                                          uemb, iemb, u1, i1);
        spmm_layer_atomic<<<blocks, threads, 0, stream>>>(a_ui, a_iu, edge_u, edge_i,
                                                          u1, i1, u2, i2);
    }
}